// Round 3
// baseline (322.738 us; speedup 1.0000x reference)
//
#include <hip/hip_runtime.h>
#include <math.h>

#define NNODE  200000
#define DIM    64
#define NF     4
#define NLAYER 2
#define KK     32
#define BB     1024

typedef __bf16 bf16x8 __attribute__((ext_vector_type(8)));
typedef float  f32x4  __attribute__((ext_vector_type(4)));

// Kernel 1: W1 (128x64 f32, row-major) -> W1T bf16 (64 x 128): w1t[d*128+i] = W1[i][d]
__global__ void prep_w1t(const float* __restrict__ W1, __bf16* __restrict__ w1t) {
    int j = blockIdx.x * 256 + threadIdx.x;   // 0..8191
    int d = j >> 7, i = j & 127;
    w1t[j] = (__bf16)W1[i * 64 + d];
}

// One block per (tower, b, layer); wave w = factor f, fully independent
// (no __syncthreads). A-fragments gathered straight from global into MFMA
// register layout; tiny 128-float LDS only for the intra-wave logit shuffle.
__global__ __launch_bounds__(256, 3) void kgat_direct(
    const float* __restrict__ node_emb,
    const __bf16* __restrict__ w1t,
    const float* __restrict__ b1,
    const float* __restrict__ W2,
    const int*   __restrict__ users,
    const int*   __restrict__ items,
    const int*   __restrict__ users_triple,
    const int*   __restrict__ items_triple,
    float*       __restrict__ out)
{
    __shared__ float logitS[128];

    const int bid   = blockIdx.x;          // 0..4095
    const int tower = bid >> 11;
    const int b     = (bid >> 1) & 1023;
    const int layer = bid & 1;
    const int tid   = threadIdx.x;
    const int w     = tid >> 6;            // wave id = factor
    const int lane  = tid & 63;
    const int m16   = lane & 15;
    const int quad  = lane >> 4;

    const int* __restrict__ triple = tower ? items_triple : users_triple;
    const int* __restrict__ idxarr = tower ? items : users;

    const int hbase = ((b * 3 + 0) * NLAYER + layer) * KK;
    const int tbase = ((b * 3 + 2) * NLAYER + layer) * KK;

    // ---- edge indices (L1/L2-hot broadcasts) ----
    int hi[2], ti[2];
    hi[0] = triple[hbase + m16];
    hi[1] = triple[hbase + 16 + m16];
    ti[0] = triple[tbase + m16];
    ti[1] = triple[tbase + 16 + m16];
    const int tkv = triple[tbase + (lane & 31)];   // for epilogue broadcast

    // ---- gather A-fragments directly: lane (m16,quad) holds
    //      X[edge = mt*16+m16][dims kt*32 + quad*8 .. +7] as bf16x8 ----
    bf16x8 Af[2][4];
#pragma unroll
    for (int mt = 0; mt < 2; ++mt) {
        const float* __restrict__ rh = node_emb + ((size_t)hi[mt] * NF + w) * DIM;
        const float* __restrict__ rt = node_emb + ((size_t)ti[mt] * NF + w) * DIM;
#pragma unroll
        for (int kt = 0; kt < 4; ++kt) {
            const float* __restrict__ src = (kt < 2 ? rh : rt) + (kt & 1) * 32 + quad * 8;
            f32x4 v0 = *(const f32x4*)src;
            f32x4 v1 = *(const f32x4*)(src + 4);
            bf16x8 a;
#pragma unroll
            for (int u = 0; u < 4; ++u) { a[u] = (__bf16)v0[u]; a[4 + u] = (__bf16)v1[u]; }
            Af[mt][kt] = a;
        }
    }

    // ---- epilogue t-values, issued early (L2-hot: lines just fetched above) ----
    float tv[KK];
#pragma unroll
    for (int k = 0; k < KK; ++k) {
        const int tk = __shfl(tkv, k, 64);
        tv[k] = node_emb[((size_t)tk * NF + w) * DIM + lane];
    }

    // ---- MFMA: hid[edge][d] for this wave's 32 edges ----
    f32x4 C[2][4];
#pragma unroll
    for (int mt = 0; mt < 2; ++mt)
#pragma unroll
        for (int nt = 0; nt < 4; ++nt) C[mt][nt] = (f32x4)(0.f);

#pragma unroll
    for (int kt = 0; kt < 4; ++kt) {
        bf16x8 Bn[4];
#pragma unroll
        for (int nt = 0; nt < 4; ++nt)
            Bn[nt] = *(const bf16x8*)(w1t + (nt * 16 + m16) * 128 + kt * 32 + quad * 8);
#pragma unroll
        for (int nt = 0; nt < 4; ++nt) {
            C[0][nt] = __builtin_amdgcn_mfma_f32_16x16x32_bf16(Af[0][kt], Bn[nt], C[0][nt], 0, 0, 0);
            C[1][nt] = __builtin_amdgcn_mfma_f32_16x16x32_bf16(Af[1][kt], Bn[nt], C[1][nt], 0, 0, 0);
        }
    }

    // ---- logits: sum_d relu(hid + b1) * W2  (b2 cancels in softmax) ----
    float b1v[4], w2v[4];
#pragma unroll
    for (int nt = 0; nt < 4; ++nt) {
        b1v[nt] = b1[nt * 16 + m16];
        w2v[nt] = W2[nt * 16 + m16];
    }
    float lsum[2][4];   // C row = quad*4 + r (edge = mt*16 + row), col = nt*16 + m16
#pragma unroll
    for (int mt = 0; mt < 2; ++mt)
#pragma unroll
        for (int r = 0; r < 4; ++r) {
            float s = 0.f;
#pragma unroll
            for (int nt = 0; nt < 4; ++nt)
                s += fmaxf(C[mt][nt][r] + b1v[nt], 0.f) * w2v[nt];
            lsum[mt][r] = s;
        }
#pragma unroll
    for (int off = 1; off < 16; off <<= 1)
#pragma unroll
        for (int mt = 0; mt < 2; ++mt)
#pragma unroll
            for (int r = 0; r < 4; ++r)
                lsum[mt][r] += __shfl_xor(lsum[mt][r], off, 64);

    // intra-wave redistribute via tiny LDS (no barrier: same-wave program order)
    if (m16 == 0) {
#pragma unroll
        for (int mt = 0; mt < 2; ++mt) {
            f32x4 v;
#pragma unroll
            for (int r = 0; r < 4; ++r) v[r] = lsum[mt][r];
            *(f32x4*)&logitS[w * 32 + mt * 16 + quad * 4] = v;
        }
    }
    const float lg = logitS[w * 32 + (lane & 31)];

    // ---- softmax over the 32 edges ----
    float mx = lg;
#pragma unroll
    for (int off = 16; off; off >>= 1) mx = fmaxf(mx, __shfl_xor(mx, off, 64));
    const float e = __expf(lg - mx);
    float s = e;
#pragma unroll
    for (int off = 16; off; off >>= 1) s += __shfl_xor(s, off, 64);
    const float wgt = e / s;   // weight for edge k = lane & 31

    // ---- output: out[f][d] = sum_k w_k * t[k][f][d]  (t in exact f32) ----
    float oacc = 0.f;
#pragma unroll
    for (int k = 0; k < KK; ++k)
        oacc += __shfl(wgt, k, 64) * tv[k];
    out[(((size_t)(tower * 3 + 1 + layer) * BB + b) * NF + w) * DIM + lane] = oacc;

    // origin row (written once, by layer==0 blocks)
    if (layer == 0) {
        const int oid = idxarr[b];
        out[(((size_t)(tower * 3 + 0) * BB + b) * NF + w) * DIM + lane] =
            node_emb[((size_t)oid * NF + w) * DIM + lane];
    }
}

extern "C" void kernel_launch(void* const* d_in, const int* in_sizes, int n_in,
                              void* d_out, int out_size, void* d_ws, size_t ws_size,
                              hipStream_t stream) {
    const float* node_emb     = (const float*)d_in[0];
    // d_in[1] = relation_emb — dead in the reference computation
    const float* W1           = (const float*)d_in[2];
    const float* b1           = (const float*)d_in[3];
    const float* W2           = (const float*)d_in[4];
    const float* b2           = (const float*)d_in[5]; (void)b2; // cancels in softmax
    const int*   users        = (const int*)d_in[6];
    const int*   items        = (const int*)d_in[7];
    const int*   users_triple = (const int*)d_in[8];
    const int*   items_triple = (const int*)d_in[9];
    float* out = (float*)d_out;

    __bf16* w1t = (__bf16*)d_ws;   // 64*128*2 = 16 KB

    hipLaunchKernelGGL(prep_w1t, dim3(32), dim3(256), 0, stream, W1, w1t);
    hipLaunchKernelGGL(kgat_direct, dim3(2 * BB * NLAYER), dim3(256), 0, stream,
                       node_emb, w1t, b1, W2,
                       users, items, users_triple, items_triple, out);
}

// Round 4
// 303.970 us; speedup vs baseline: 1.0617x; 1.0617x over previous
//
#include <hip/hip_runtime.h>
#include <math.h>

#define NNODE  200000
#define DIM    64
#define NF     4
#define NLAYER 2
#define KK     32
#define BB     1024

typedef __bf16 bf16x8 __attribute__((ext_vector_type(8)));
typedef float  f32x4  __attribute__((ext_vector_type(4)));

// Kernel 1: W1 (128x64 f32, row-major) -> W1T bf16 (64 x 128): w1t[d*128+i] = W1[i][d]
__global__ void prep_w1t(const float* __restrict__ W1, __bf16* __restrict__ w1t) {
    int j = blockIdx.x * 256 + threadIdx.x;   // 0..8191
    int d = j >> 7, i = j & 127;
    w1t[j] = (__bf16)W1[i * 64 + d];
}

// One block per (tower, b, layer); wave w = factor f, fully independent
// (no __syncthreads). A-fragments gathered straight from global into MFMA
// register layout; epilogue weighted t-sum computed FROM THE SAME REGISTERS
// (no re-read of t rows). Tiny LDS only for intra-wave redistributes.
__global__ __launch_bounds__(256, 4) void kgat_direct(
    const float* __restrict__ node_emb,
    const __bf16* __restrict__ w1t,
    const float* __restrict__ b1,
    const float* __restrict__ W2,
    const int*   __restrict__ users,
    const int*   __restrict__ items,
    const int*   __restrict__ users_triple,
    const int*   __restrict__ items_triple,
    float*       __restrict__ out)
{
    __shared__ float logitS[128];
    __shared__ float outS[256];

    const int bid   = blockIdx.x;          // 0..4095
    const int tower = bid >> 11;
    const int b     = (bid >> 1) & 1023;
    const int layer = bid & 1;
    const int tid   = threadIdx.x;
    const int w     = tid >> 6;            // wave id = factor
    const int lane  = tid & 63;
    const int m16   = lane & 15;
    const int quad  = lane >> 4;

    const int* __restrict__ triple = tower ? items_triple : users_triple;
    const int* __restrict__ idxarr = tower ? items : users;

    const int hbase = ((b * 3 + 0) * NLAYER + layer) * KK;
    const int tbase = ((b * 3 + 2) * NLAYER + layer) * KK;

    // ---- edge indices (L1/L2-hot broadcasts) ----
    int hi[2], ti[2];
    hi[0] = triple[hbase + m16];
    hi[1] = triple[hbase + 16 + m16];
    ti[0] = triple[tbase + m16];
    ti[1] = triple[tbase + 16 + m16];

    // ---- gather A-fragments directly: lane (m16,quad) holds
    //      X[edge = mt*16+m16][dims kt*32 + quad*8 .. +7] as bf16x8
    //      kt 0,1 = h row ; kt 2,3 = t row ----
    bf16x8 Af[2][4];
#pragma unroll
    for (int mt = 0; mt < 2; ++mt) {
        const float* __restrict__ rh = node_emb + ((size_t)hi[mt] * NF + w) * DIM;
        const float* __restrict__ rt = node_emb + ((size_t)ti[mt] * NF + w) * DIM;
#pragma unroll
        for (int kt = 0; kt < 4; ++kt) {
            const float* __restrict__ src = (kt < 2 ? rh : rt) + (kt & 1) * 32 + quad * 8;
            f32x4 v0 = *(const f32x4*)src;
            f32x4 v1 = *(const f32x4*)(src + 4);
            bf16x8 a;
#pragma unroll
            for (int u = 0; u < 4; ++u) { a[u] = (__bf16)v0[u]; a[4 + u] = (__bf16)v1[u]; }
            Af[mt][kt] = a;
        }
    }

    // ---- MFMA: hid[edge][d] for this wave's 32 edges ----
    f32x4 C[2][4];
#pragma unroll
    for (int mt = 0; mt < 2; ++mt)
#pragma unroll
        for (int nt = 0; nt < 4; ++nt) C[mt][nt] = (f32x4)(0.f);

#pragma unroll
    for (int kt = 0; kt < 4; ++kt) {
        bf16x8 Bn[4];
#pragma unroll
        for (int nt = 0; nt < 4; ++nt)
            Bn[nt] = *(const bf16x8*)(w1t + (nt * 16 + m16) * 128 + kt * 32 + quad * 8);
#pragma unroll
        for (int nt = 0; nt < 4; ++nt) {
            C[0][nt] = __builtin_amdgcn_mfma_f32_16x16x32_bf16(Af[0][kt], Bn[nt], C[0][nt], 0, 0, 0);
            C[1][nt] = __builtin_amdgcn_mfma_f32_16x16x32_bf16(Af[1][kt], Bn[nt], C[1][nt], 0, 0, 0);
        }
    }

    // ---- logits: sum_d relu(hid + b1) * W2  (b2 cancels in softmax) ----
    float b1v[4], w2v[4];
#pragma unroll
    for (int nt = 0; nt < 4; ++nt) {
        b1v[nt] = b1[nt * 16 + m16];
        w2v[nt] = W2[nt * 16 + m16];
    }
    float lsum[2][4];   // C row = quad*4 + r (edge = mt*16 + row), col = nt*16 + m16
#pragma unroll
    for (int mt = 0; mt < 2; ++mt)
#pragma unroll
        for (int r = 0; r < 4; ++r) {
            float s = 0.f;
#pragma unroll
            for (int nt = 0; nt < 4; ++nt)
                s += fmaxf(C[mt][nt][r] + b1v[nt], 0.f) * w2v[nt];
            lsum[mt][r] = s;
        }
#pragma unroll
    for (int off = 1; off < 16; off <<= 1)
#pragma unroll
        for (int mt = 0; mt < 2; ++mt)
#pragma unroll
            for (int r = 0; r < 4; ++r)
                lsum[mt][r] += __shfl_xor(lsum[mt][r], off, 64);

    // intra-wave redistribute via tiny LDS (no barrier: same-wave program order)
    if (m16 == 0) {
#pragma unroll
        for (int mt = 0; mt < 2; ++mt) {
            f32x4 v;
#pragma unroll
            for (int r = 0; r < 4; ++r) v[r] = lsum[mt][r];
            *(f32x4*)&logitS[w * 32 + mt * 16 + quad * 4] = v;
        }
    }
    const float lg = logitS[w * 32 + (lane & 31)];

    // ---- softmax over the 32 edges ----
    float mx = lg;
#pragma unroll
    for (int off = 16; off; off >>= 1) mx = fmaxf(mx, __shfl_xor(mx, off, 64));
    const float e = __expf(lg - mx);
    float s = e;
#pragma unroll
    for (int off = 16; off; off >>= 1) s += __shfl_xor(s, off, 64);
    const float wgt = e / s;   // weight for edge k = lane & 31 (both 32-halves identical)

    // ---- output from registers: out[d] = sum_k w_k * t[k][d] ----
    // Lane (m16,quad) holds t[mt*16+m16][quad*8+j] in Af[mt][2][j]
    //                  and t[mt*16+m16][32+quad*8+j] in Af[mt][3][j].
    float o0[8], o1[8];
#pragma unroll
    for (int j = 0; j < 8; ++j) { o0[j] = 0.f; o1[j] = 0.f; }
#pragma unroll
    for (int mt = 0; mt < 2; ++mt) {
        const float wv = __shfl(wgt, mt * 16 + m16, 64);
#pragma unroll
        for (int j = 0; j < 8; ++j) {
            o0[j] += wv * (float)Af[mt][2][j];
            o1[j] += wv * (float)Af[mt][3][j];
        }
    }
    // reduce across the 16 m16-lanes (same quad): offsets 1,2,4,8
#pragma unroll
    for (int off = 1; off < 16; off <<= 1)
#pragma unroll
        for (int j = 0; j < 8; ++j) {
            o0[j] += __shfl_xor(o0[j], off, 64);
            o1[j] += __shfl_xor(o1[j], off, 64);
        }
    if (m16 == 0) {
        f32x4 v;
#pragma unroll
        for (int j = 0; j < 4; ++j) v[j] = o0[j];
        *(f32x4*)&outS[w * 64 + quad * 8] = v;
#pragma unroll
        for (int j = 0; j < 4; ++j) v[j] = o0[4 + j];
        *(f32x4*)&outS[w * 64 + quad * 8 + 4] = v;
#pragma unroll
        for (int j = 0; j < 4; ++j) v[j] = o1[j];
        *(f32x4*)&outS[w * 64 + 32 + quad * 8] = v;
#pragma unroll
        for (int j = 0; j < 4; ++j) v[j] = o1[4 + j];
        *(f32x4*)&outS[w * 64 + 32 + quad * 8 + 4] = v;
    }
    out[(((size_t)(tower * 3 + 1 + layer) * BB + b) * NF + w) * DIM + lane] =
        outS[w * 64 + lane];

    // origin row (written once, by layer==0 blocks)
    if (layer == 0) {
        const int oid = idxarr[b];
        out[(((size_t)(tower * 3 + 0) * BB + b) * NF + w) * DIM + lane] =
            node_emb[((size_t)oid * NF + w) * DIM + lane];
    }
}

extern "C" void kernel_launch(void* const* d_in, const int* in_sizes, int n_in,
                              void* d_out, int out_size, void* d_ws, size_t ws_size,
                              hipStream_t stream) {
    const float* node_emb     = (const float*)d_in[0];
    // d_in[1] = relation_emb — dead in the reference computation
    const float* W1           = (const float*)d_in[2];
    const float* b1           = (const float*)d_in[3];
    const float* W2           = (const float*)d_in[4];
    const float* b2           = (const float*)d_in[5]; (void)b2; // cancels in softmax
    const int*   users        = (const int*)d_in[6];
    const int*   items        = (const int*)d_in[7];
    const int*   users_triple = (const int*)d_in[8];
    const int*   items_triple = (const int*)d_in[9];
    float* out = (float*)d_out;

    __bf16* w1t = (__bf16*)d_ws;   // 64*128*2 = 16 KB

    hipLaunchKernelGGL(prep_w1t, dim3(32), dim3(256), 0, stream, W1, w1t);
    hipLaunchKernelGGL(kgat_direct, dim3(2 * BB * NLAYER), dim3(256), 0, stream,
                       node_emb, w1t, b1, W2,
                       users, items, users_triple, items_triple, out);
}